// Round 2
// baseline (325.030 us; speedup 1.0000x reference)
//
#include <hip/hip_runtime.h>
#include <cstdint>
#include <cstddef>

#define Bn 64
#define Tn 2048
#define Un 512
#define QSn 512
#define MSn 512

using f32x16 = __attribute__((ext_vector_type(16))) float;
using bf16x8 = __attribute__((ext_vector_type(8))) short;

__device__ __forceinline__ unsigned short f2bf(float x) {
    unsigned int u = __float_as_uint(x);
    u += 0x7FFFu + ((u >> 16) & 1u);
    return (unsigned short)(u >> 16);
}

__device__ __forceinline__ float tanh_fast(float x) {
    // tanh(x) = 1 - 2/(e^{2x}+1); clamp so exp2 can't overflow. |err| ~1e-6.
    float xc = fminf(fmaxf(x, -9.f), 9.f);
    float e = exp2f(xc * 2.885390043258667f);   // e^{2x}
    return 1.f - 2.f * __builtin_amdgcn_rcpf(e + 1.f);
}

// ---------------- Wm f32 -> bf16 pre-convert ----------------
__global__ __launch_bounds__(256) void cvt_kernel(const float* __restrict__ src,
                                                  unsigned short* __restrict__ dst) {
    int i = blockIdx.x * 256 + threadIdx.x;  // one float4 per thread
    float4 v = *(const float4*)(src + (size_t)i * 4);
    ushort4 h = { f2bf(v.x), f2bf(v.y), f2bf(v.z), f2bf(v.w) };
    *(ushort4*)&dst[(size_t)i * 4] = h;
}

// ---------------- pq = query @ Wq^T : [B,U] ----------------
__global__ __launch_bounds__(128) void pq_kernel(const float* __restrict__ query,
                                                 const float* __restrict__ Wq,
                                                 float* __restrict__ pq) {
    __shared__ float ql[QSn];
    const int b = blockIdx.x;
    const int quad = blockIdx.y;
    const int tid = threadIdx.x;
    for (int i = tid; i < QSn; i += 128) ql[i] = query[(size_t)b * QSn + i];
    __syncthreads();
    const int u = quad * 128 + tid;
    const float* w = Wq + (size_t)u * QSn;
    float a0 = 0.f, a1 = 0.f;
    #pragma unroll 4
    for (int k = 0; k < QSn; k += 8) {
        float4 w0 = *(const float4*)(w + k);
        float4 w1 = *(const float4*)(w + k + 4);
        float4 q0 = *(const float4*)(ql + k);
        float4 q1 = *(const float4*)(ql + k + 4);
        a0 += w0.x * q0.x + w0.y * q0.y + w0.z * q0.z + w0.w * q0.w;
        a1 += w1.x * q1.x + w1.y * q1.y + w1.z * q1.z + w1.w * q1.w;
    }
    pq[(size_t)b * Un + u] = a0 + a1;
}

// ---------------- fused score GEMM (v2: A-in-LDS, B-from-L2) ----------------
// 256 threads = 4 waves. Block tile: TM=64 t-rows x FULL U=512.
// Wave w owns u-range [w*128, w*128+128): 2(m) x 4(n) mfma_32x32x16 frags.
// A (keys f32->bf16) double-buffered in LDS, BK=64, XOR-swizzled granules,
// ONE barrier per K-tile. B (Wm bf16, 512KB, L2-resident) loaded per-wave
// straight from global -> regs each k-step: no B-LDS, no extra barriers.
#define TM 64
#define BKt 64

__global__ __launch_bounds__(256) void score_kernel(const float* __restrict__ keys,
                                                    const unsigned short* __restrict__ WmB,
                                                    const float* __restrict__ pq,
                                                    const float* __restrict__ Wa,
                                                    float* __restrict__ score) {
    __shared__ __align__(16) unsigned short Alds[2][TM * BKt];  // 16 KB
    __shared__ float sc_lds[4][TM];

    const int tid = threadIdx.x;
    const int lane = tid & 63;
    const int w = tid >> 6;        // wave id = u-group 0..3
    const int lc = lane & 31;
    const int l5 = lane >> 5;
    const int b = blockIdx.y;
    const int t0 = blockIdx.x * TM;

    // ---- staging geometry: thread covers rows {srow, srow+32}, cols scol..scol+7
    const int srow = tid >> 3;           // 0..31
    const int sg   = tid & 7;            // granule 0..7
    const int scol = sg * 8;
    const float* gA = keys + ((size_t)(b * Tn + t0 + srow)) * MSn + scol;
    const int pg0 = sg ^ (srow & 7);     // rows r and r+32 share (r&7)
    unsigned short* wdst0 = &Alds[0][srow * BKt + pg0 * 8];
    unsigned short* wdst1 = &Alds[0][(srow + 32) * BKt + pg0 * 8];
    const int bufStride = TM * BKt;

    // ---- B pointer (per-lane, nf adds 32 rows)
    const unsigned short* gB = WmB + ((size_t)(w * 128 + lc)) * MSn + l5 * 8;

    f32x16 acc[2][4];
    #pragma unroll
    for (int mf = 0; mf < 2; ++mf)
        #pragma unroll
        for (int nf = 0; nf < 4; ++nf)
            #pragma unroll
            for (int r = 0; r < 16; ++r) acc[mf][nf][r] = 0.f;

    // ---- prologue: stage K-tile 0
    {
        float4 a0 = *(const float4*)(gA);
        float4 a1 = *(const float4*)(gA + 4);
        float4 a2 = *(const float4*)(gA + (size_t)32 * MSn);
        float4 a3 = *(const float4*)(gA + (size_t)32 * MSn + 4);
        bf16x8 h0 = { (short)f2bf(a0.x), (short)f2bf(a0.y), (short)f2bf(a0.z), (short)f2bf(a0.w),
                      (short)f2bf(a1.x), (short)f2bf(a1.y), (short)f2bf(a1.z), (short)f2bf(a1.w) };
        bf16x8 h1 = { (short)f2bf(a2.x), (short)f2bf(a2.y), (short)f2bf(a2.z), (short)f2bf(a2.w),
                      (short)f2bf(a3.x), (short)f2bf(a3.y), (short)f2bf(a3.z), (short)f2bf(a3.w) };
        *(bf16x8*)wdst0 = h0;
        *(bf16x8*)wdst1 = h1;
    }
    __syncthreads();

    // A-frag LDS offsets (ushort units): row r, granule g=ks*2+l5, phys g^(r&7)
    #pragma unroll 2
    for (int kt = 0; kt < 8; ++kt) {
        const int bi = kt & 1;
        // issue next tile's global loads EARLY (hide HBM under this tile's MFMA)
        float4 n0, n1, n2, n3;
        if (kt < 7) {
            const float* g = gA + (kt + 1) * BKt;
            n0 = *(const float4*)(g);
            n1 = *(const float4*)(g + 4);
            n2 = *(const float4*)(g + (size_t)32 * MSn);
            n3 = *(const float4*)(g + (size_t)32 * MSn + 4);
        }
        const unsigned short* gBk = gB + kt * BKt;
        const unsigned short* lA = &Alds[bi][0];
        #pragma unroll
        for (int ks = 0; ks < 4; ++ks) {
            bf16x8 bfr[4];
            #pragma unroll
            for (int nf = 0; nf < 4; ++nf)
                bfr[nf] = *(const bf16x8*)(gBk + (size_t)nf * 32 * MSn + ks * 16);
            bf16x8 af[2];
            #pragma unroll
            for (int mf = 0; mf < 2; ++mf) {
                int r = mf * 32 + lc;
                int g = ks * 2 + l5;
                af[mf] = *(const bf16x8*)&lA[r * BKt + (g ^ (r & 7)) * 8];
            }
            #pragma unroll
            for (int mf = 0; mf < 2; ++mf)
                #pragma unroll
                for (int nf = 0; nf < 4; ++nf)
                    acc[mf][nf] = __builtin_amdgcn_mfma_f32_32x32x16_bf16(
                        af[mf], bfr[nf], acc[mf][nf], 0, 0, 0);
        }
        // write next tile LATE, then one barrier
        if (kt < 7) {
            bf16x8 h0 = { (short)f2bf(n0.x), (short)f2bf(n0.y), (short)f2bf(n0.z), (short)f2bf(n0.w),
                          (short)f2bf(n1.x), (short)f2bf(n1.y), (short)f2bf(n1.z), (short)f2bf(n1.w) };
            bf16x8 h1 = { (short)f2bf(n2.x), (short)f2bf(n2.y), (short)f2bf(n2.z), (short)f2bf(n2.w),
                          (short)f2bf(n3.x), (short)f2bf(n3.y), (short)f2bf(n3.z), (short)f2bf(n3.w) };
            const int nb = (bi ^ 1) * bufStride;
            *(bf16x8*)(wdst0 + nb) = h0;
            *(bf16x8*)(wdst1 + nb) = h1;
        }
        __syncthreads();
    }

    // ---- epilogue: score[t] = sum_u tanh(vals + pq[u]) * Wa[u]
    // C layout: col(u) = lc, row(t) = mf*32 + (r&3) + 8*(r>>2) + 4*l5
    float pqv[4], wav[4];
    #pragma unroll
    for (int nf = 0; nf < 4; ++nf) {
        int u = w * 128 + nf * 32 + lc;
        pqv[nf] = pq[(size_t)b * Un + u];
        wav[nf] = Wa[u];
    }
    #pragma unroll
    for (int mf = 0; mf < 2; ++mf) {
        #pragma unroll
        for (int r = 0; r < 16; ++r) {
            float s = 0.f;
            #pragma unroll
            for (int nf = 0; nf < 4; ++nf)
                s += tanh_fast(acc[mf][nf][r] + pqv[nf]) * wav[nf];
            s += __shfl_xor(s, 16);
            s += __shfl_xor(s, 8);
            s += __shfl_xor(s, 4);
            s += __shfl_xor(s, 2);
            s += __shfl_xor(s, 1);
            if (lc == 0)
                sc_lds[w][mf * 32 + (r & 3) + 8 * (r >> 2) + 4 * l5] = s;
        }
    }
    __syncthreads();
    if (tid < TM) {
        float s = sc_lds[0][tid] + sc_lds[1][tid] + sc_lds[2][tid] + sc_lds[3][tid];
        score[(size_t)b * Tn + t0 + tid] = s;
    }
}

// ---------------- softmax over T per batch ----------------
__global__ __launch_bounds__(256) void softmax_kernel(const float* __restrict__ score,
                                                      float* __restrict__ weight) {
    const int b = blockIdx.x, tid = threadIdx.x;
    const int lane = tid & 63, wid = tid >> 6;
    __shared__ float red[4];
    const float* s = score + (size_t)b * Tn;
    float v[8];
    float mx = -1e30f;
    #pragma unroll
    for (int i = 0; i < 8; ++i) { v[i] = s[tid + i * 256]; mx = fmaxf(mx, v[i]); }
    #pragma unroll
    for (int off = 32; off; off >>= 1) mx = fmaxf(mx, __shfl_xor(mx, off));
    if (lane == 0) red[wid] = mx;
    __syncthreads();
    mx = fmaxf(fmaxf(red[0], red[1]), fmaxf(red[2], red[3]));
    float sum = 0.f;
    #pragma unroll
    for (int i = 0; i < 8; ++i) { v[i] = expf(v[i] - mx); sum += v[i]; }
    #pragma unroll
    for (int off = 32; off; off >>= 1) sum += __shfl_xor(sum, off);
    __syncthreads();
    if (lane == 0) red[wid] = sum;
    __syncthreads();
    sum = red[0] + red[1] + red[2] + red[3];
    float inv = 1.f / sum;
    #pragma unroll
    for (int i = 0; i < 8; ++i) weight[(size_t)b * Tn + tid + i * 256] = v[i] * inv;
}

// ---------------- context partials: 16 t-chunks per batch ----------------
__global__ __launch_bounds__(256) void ctx_partial_kernel(const float* __restrict__ keys,
                                                          const float* __restrict__ weight,
                                                          float* __restrict__ partial) {
    __shared__ float wl[128];
    const int b = blockIdx.x, chunk = blockIdx.y, tid = threadIdx.x;
    const int t0 = chunk * 128;
    if (tid < 128) wl[tid] = weight[(size_t)b * Tn + t0 + tid];
    __syncthreads();
    float2 acc = { 0.f, 0.f };
    const float2* kp = (const float2*)(keys + ((size_t)b * Tn + t0) * MSn);
    #pragma unroll 4
    for (int t = 0; t < 128; ++t) {
        float2 kv = kp[(size_t)t * (MSn / 2) + tid];
        float w = wl[t];
        acc.x += w * kv.x;
        acc.y += w * kv.y;
    }
    *(float2*)&partial[((size_t)b * 16 + chunk) * MSn + tid * 2] = acc;
}

// ---------------- reduce partials -> total_context ----------------
__global__ __launch_bounds__(512) void ctx_reduce_kernel(const float* __restrict__ partial,
                                                         float* __restrict__ ctx) {
    const int b = blockIdx.x, m = threadIdx.x;
    float s = 0.f;
    #pragma unroll
    for (int c = 0; c < 16; ++c) s += partial[((size_t)b * 16 + c) * MSn + m];
    ctx[(size_t)b * MSn + m] = s;
}

extern "C" void kernel_launch(void* const* d_in, const int* in_sizes, int n_in,
                              void* d_out, int out_size, void* d_ws, size_t ws_size,
                              hipStream_t stream) {
    const float* query = (const float*)d_in[0];
    const float* keys  = (const float*)d_in[1];
    const float* Wq    = (const float*)d_in[2];
    const float* Wm    = (const float*)d_in[3];
    const float* Wa    = (const float*)d_in[4];

    float* ctx_out   = (float*)d_out;                    // [64][512]
    float* score_out = (float*)d_out + (size_t)Bn * MSn; // [64][2048]

    char* ws = (char*)d_ws;
    float* ws_pq      = (float*)(ws);                    // 128 KB
    float* ws_weight  = (float*)(ws + 131072);           // 512 KB
    float* ws_partial = (float*)(ws + 655360);           // 2 MB
    unsigned short* ws_wmbf = (unsigned short*)(ws + 2752512);  // 512 KB

    cvt_kernel<<<(Un * MSn / 4) / 256, 256, 0, stream>>>(Wm, ws_wmbf);
    pq_kernel<<<dim3(Bn, 4), 128, 0, stream>>>(query, Wq, ws_pq);
    score_kernel<<<dim3(Tn / TM, Bn), 256, 0, stream>>>(keys, ws_wmbf, ws_pq, Wa, score_out);
    softmax_kernel<<<Bn, 256, 0, stream>>>(score_out, ws_weight);
    ctx_partial_kernel<<<dim3(Bn, 16), 256, 0, stream>>>(keys, ws_weight, ws_partial);
    ctx_reduce_kernel<<<Bn, 512, 0, stream>>>(ws_partial, ctx_out);
}

// Round 3
// 230.621 us; speedup vs baseline: 1.4094x; 1.4094x over previous
//
#include <hip/hip_runtime.h>
#include <cstdint>
#include <cstddef>

#define Bn 64
#define Tn 2048
#define Un 512
#define QSn 512
#define MSn 512

using f32x16 = __attribute__((ext_vector_type(16))) float;
using bf16x8 = __attribute__((ext_vector_type(8))) short;

__device__ __forceinline__ unsigned short f2bf(float x) {
    unsigned int u = __float_as_uint(x);
    u += 0x7FFFu + ((u >> 16) & 1u);
    return (unsigned short)(u >> 16);
}

__device__ __forceinline__ float tanh_fast(float x) {
    // tanh(x) = 1 - 2/(e^{2x}+1); clamp so exp can't overflow. |err| ~1e-6.
    float xc = fminf(fmaxf(x, -9.f), 9.f);
    float e = exp2f(xc * 2.885390043258667f);   // e^{2x}
    return 1.f - 2.f * __builtin_amdgcn_rcpf(e + 1.f);
}

// ---------------- Wm f32 -> bf16 pre-convert ----------------
__global__ __launch_bounds__(256) void cvt_kernel(const float* __restrict__ src,
                                                  unsigned short* __restrict__ dst) {
    int i = blockIdx.x * 256 + threadIdx.x;  // one float4 per thread
    float4 v = *(const float4*)(src + (size_t)i * 4);
    ushort4 h = { f2bf(v.x), f2bf(v.y), f2bf(v.z), f2bf(v.w) };
    *(ushort4*)&dst[(size_t)i * 4] = h;
}

// ---------------- pq = query @ Wq^T : [B,U] ----------------
__global__ __launch_bounds__(128) void pq_kernel(const float* __restrict__ query,
                                                 const float* __restrict__ Wq,
                                                 float* __restrict__ pq) {
    __shared__ float ql[QSn];
    const int b = blockIdx.x;
    const int quad = blockIdx.y;
    const int tid = threadIdx.x;
    for (int i = tid; i < QSn; i += 128) ql[i] = query[(size_t)b * QSn + i];
    __syncthreads();
    const int u = quad * 128 + tid;
    const float* w = Wq + (size_t)u * QSn;
    float a0 = 0.f, a1 = 0.f;
    #pragma unroll 4
    for (int k = 0; k < QSn; k += 8) {
        float4 w0 = *(const float4*)(w + k);
        float4 w1 = *(const float4*)(w + k + 4);
        float4 q0 = *(const float4*)(ql + k);
        float4 q1 = *(const float4*)(ql + k + 4);
        a0 += w0.x * q0.x + w0.y * q0.y + w0.z * q0.z + w0.w * q0.w;
        a1 += w1.x * q1.x + w1.y * q1.y + w1.z * q1.z + w1.w * q1.w;
    }
    pq[(size_t)b * Un + u] = a0 + a1;
}

// ---------------- fused score GEMM (v3) ----------------
// 256 threads = 4 waves. Block tile: 64 t-rows x 256 u (U split across 2 blocks;
// partial scores merged in softmax kernel). Wave tile 64x64 = 2x2 mfma32 frags
// -> acc only 64 regs/wave -> 3 blocks/CU resident.
// Per k-tile (BK=64) issue order (vmcnt is FIFO!):
//   barrier -> 8 B-loads (L2) -> sched_barrier -> 4 A-loads kt+1 (HBM)
//   -> ds_read A-frags + MFMAs (B waits leave newer A in flight)
//   -> f32->bf16 cvt + swizzled ds_write (vmcnt(0) lands after MFMA phase).
#define TM 64
#define BKt 64

__global__ __launch_bounds__(256, 3) void score_kernel(const float* __restrict__ keys,
                                                       const unsigned short* __restrict__ WmB,
                                                       const float* __restrict__ pq,
                                                       const float* __restrict__ Wa,
                                                       float* __restrict__ spart) {
    __shared__ __align__(16) unsigned short Alds[2][TM * BKt];  // 16 KB
    __shared__ float sc_lds[4][TM];

    const int tid = threadIdx.x;
    const int lane = tid & 63;
    const int w = tid >> 6;        // wave id 0..3
    const int lc = lane & 31;
    const int l5 = lane >> 5;
    const int b = blockIdx.y;
    const int tt = blockIdx.x >> 1;
    const int uh = blockIdx.x & 1;
    const int t0 = tt * TM;
    const int u0 = uh * 256 + w * 64;

    // ---- A staging: thread owns row=tid>>2, 16 f32 cols starting at (tid&3)*16
    const int srow = tid >> 2;
    const int scg  = (tid & 3) * 2;            // two 8-elem granules scg, scg+1
    const float* gA = keys + ((size_t)(b * Tn + t0 + srow)) * MSn + scg * 8;
    const int woff0 = srow * BKt + ((scg ^ (srow & 7)) * 8);
    const int woff1 = srow * BKt + (((scg + 1) ^ (srow & 7)) * 8);

    // ---- B pointers (bf16 Wm, L2-resident)
    const unsigned short* gB0 = WmB + ((size_t)(u0 + lc)) * MSn + l5 * 8;
    const unsigned short* gB1 = gB0 + (size_t)32 * MSn;

    f32x16 acc[2][2];
    #pragma unroll
    for (int mf = 0; mf < 2; ++mf)
        #pragma unroll
        for (int nf = 0; nf < 2; ++nf)
            #pragma unroll
            for (int r = 0; r < 16; ++r) acc[mf][nf][r] = 0.f;

    // ---- prologue: stage k-tile 0
    {
        float4 a0 = *(const float4*)(gA);
        float4 a1 = *(const float4*)(gA + 4);
        float4 a2 = *(const float4*)(gA + 8);
        float4 a3 = *(const float4*)(gA + 12);
        bf16x8 h0 = { (short)f2bf(a0.x), (short)f2bf(a0.y), (short)f2bf(a0.z), (short)f2bf(a0.w),
                      (short)f2bf(a1.x), (short)f2bf(a1.y), (short)f2bf(a1.z), (short)f2bf(a1.w) };
        bf16x8 h1 = { (short)f2bf(a2.x), (short)f2bf(a2.y), (short)f2bf(a2.z), (short)f2bf(a2.w),
                      (short)f2bf(a3.x), (short)f2bf(a3.y), (short)f2bf(a3.z), (short)f2bf(a3.w) };
        *(bf16x8*)&Alds[0][woff0] = h0;
        *(bf16x8*)&Alds[0][woff1] = h1;
    }

    #pragma unroll
    for (int kt = 0; kt < 8; ++kt) {
        const int buf = kt & 1;
        __syncthreads();   // compiler drains vmcnt(0) lgkmcnt(0): buf is ready

        // 1) all B-loads for this kt (oldest in vmcnt queue)
        bf16x8 bfr[4][2];
        #pragma unroll
        for (int ks = 0; ks < 4; ++ks) {
            bfr[ks][0] = *(const bf16x8*)(gB0 + kt * BKt + ks * 16);
            bfr[ks][1] = *(const bf16x8*)(gB1 + kt * BKt + ks * 16);
        }
        __builtin_amdgcn_sched_barrier(0);  // pin: A-loads must stay AFTER B-loads

        // 2) A f32 loads for kt+1 (newer than B: B-waits won't drain them)
        float4 a0, a1, a2, a3;
        if (kt < 7) {
            const float* g = gA + (kt + 1) * BKt;
            a0 = *(const float4*)(g);
            a1 = *(const float4*)(g + 4);
            a2 = *(const float4*)(g + 8);
            a3 = *(const float4*)(g + 12);
        }

        // 3) MFMAs on current tile
        #pragma unroll
        for (int ks = 0; ks < 4; ++ks) {
            bf16x8 af[2];
            #pragma unroll
            for (int mf = 0; mf < 2; ++mf) {
                int r = mf * 32 + lc;
                int g = ks * 2 + l5;
                af[mf] = *(const bf16x8*)&Alds[buf][r * BKt + ((g ^ (r & 7)) * 8)];
            }
            #pragma unroll
            for (int mf = 0; mf < 2; ++mf)
                #pragma unroll
                for (int nf = 0; nf < 2; ++nf)
                    acc[mf][nf] = __builtin_amdgcn_mfma_f32_32x32x16_bf16(
                        af[mf], bfr[ks][nf], acc[mf][nf], 0, 0, 0);
        }

        // 4) convert + write kt+1 into the other buffer (vmcnt(0) here, covered)
        if (kt < 7) {
            bf16x8 h0 = { (short)f2bf(a0.x), (short)f2bf(a0.y), (short)f2bf(a0.z), (short)f2bf(a0.w),
                          (short)f2bf(a1.x), (short)f2bf(a1.y), (short)f2bf(a1.z), (short)f2bf(a1.w) };
            bf16x8 h1 = { (short)f2bf(a2.x), (short)f2bf(a2.y), (short)f2bf(a2.z), (short)f2bf(a2.w),
                          (short)f2bf(a3.x), (short)f2bf(a3.y), (short)f2bf(a3.z), (short)f2bf(a3.w) };
            *(bf16x8*)&Alds[buf ^ 1][woff0] = h0;
            *(bf16x8*)&Alds[buf ^ 1][woff1] = h1;
        }
    }

    // ---- epilogue: partial score = sum_{u in block} tanh(vals + pq[u]) * Wa[u]
    // C layout: col(u) = lc, row(t) = mf*32 + (r&3) + 8*(r>>2) + 4*l5
    float pqv[2], wav[2];
    #pragma unroll
    for (int nf = 0; nf < 2; ++nf) {
        int u = u0 + nf * 32 + lc;
        pqv[nf] = pq[(size_t)b * Un + u];
        wav[nf] = Wa[u];
    }
    #pragma unroll
    for (int mf = 0; mf < 2; ++mf) {
        #pragma unroll
        for (int r = 0; r < 16; ++r) {
            float s = tanh_fast(acc[mf][0][r] + pqv[0]) * wav[0]
                    + tanh_fast(acc[mf][1][r] + pqv[1]) * wav[1];
            s += __shfl_xor(s, 16);
            s += __shfl_xor(s, 8);
            s += __shfl_xor(s, 4);
            s += __shfl_xor(s, 2);
            s += __shfl_xor(s, 1);
            if (lc == 0)
                sc_lds[w][mf * 32 + (r & 3) + 8 * (r >> 2) + 4 * l5] = s;
        }
    }
    __syncthreads();
    if (tid < TM) {
        float s = sc_lds[0][tid] + sc_lds[1][tid] + sc_lds[2][tid] + sc_lds[3][tid];
        spart[((size_t)(uh * Bn + b)) * Tn + t0 + tid] = s;
    }
}

// ---------------- merge partials + softmax ----------------
__global__ __launch_bounds__(256) void softmax_kernel(const float* __restrict__ spart,
                                                      float* __restrict__ score_out,
                                                      float* __restrict__ weight) {
    const int b = blockIdx.x, tid = threadIdx.x;
    const int lane = tid & 63, wid = tid >> 6;
    __shared__ float red[4];
    const float* s0 = spart + (size_t)b * Tn;
    const float* s1 = spart + ((size_t)(Bn + b)) * Tn;
    float v[8];
    float mx = -1e30f;
    #pragma unroll
    for (int i = 0; i < 8; ++i) {
        int t = tid + i * 256;
        v[i] = s0[t] + s1[t];
        score_out[(size_t)b * Tn + t] = v[i];
        mx = fmaxf(mx, v[i]);
    }
    #pragma unroll
    for (int off = 32; off; off >>= 1) mx = fmaxf(mx, __shfl_xor(mx, off));
    if (lane == 0) red[wid] = mx;
    __syncthreads();
    mx = fmaxf(fmaxf(red[0], red[1]), fmaxf(red[2], red[3]));
    float sum = 0.f;
    #pragma unroll
    for (int i = 0; i < 8; ++i) { v[i] = expf(v[i] - mx); sum += v[i]; }
    #pragma unroll
    for (int off = 32; off; off >>= 1) sum += __shfl_xor(sum, off);
    __syncthreads();
    if (lane == 0) red[wid] = sum;
    __syncthreads();
    sum = red[0] + red[1] + red[2] + red[3];
    float inv = 1.f / sum;
    #pragma unroll
    for (int i = 0; i < 8; ++i) weight[(size_t)b * Tn + tid + i * 256] = v[i] * inv;
}

// ---------------- context partials: 16 t-chunks per batch, float4/lane ----------------
__global__ __launch_bounds__(128) void ctx_partial_kernel(const float* __restrict__ keys,
                                                          const float* __restrict__ weight,
                                                          float* __restrict__ partial) {
    __shared__ float wl[128];
    const int b = blockIdx.x, chunk = blockIdx.y, tid = threadIdx.x;
    const int t0 = chunk * 128;
    if (tid < 128) wl[tid] = weight[(size_t)b * Tn + t0 + tid];
    __syncthreads();
    float4 acc = { 0.f, 0.f, 0.f, 0.f };
    const float4* kp = (const float4*)(keys + ((size_t)b * Tn + t0) * MSn) + tid;
    #pragma unroll 4
    for (int t = 0; t < 128; ++t) {
        float4 kv = kp[(size_t)t * (MSn / 4)];
        float w = wl[t];
        acc.x += w * kv.x;
        acc.y += w * kv.y;
        acc.z += w * kv.z;
        acc.w += w * kv.w;
    }
    *(float4*)&partial[((size_t)b * 16 + chunk) * MSn + tid * 4] = acc;
}

// ---------------- reduce partials -> total_context ----------------
__global__ __launch_bounds__(512) void ctx_reduce_kernel(const float* __restrict__ partial,
                                                         float* __restrict__ ctx) {
    const int b = blockIdx.x, m = threadIdx.x;
    float s = 0.f;
    #pragma unroll
    for (int c = 0; c < 16; ++c) s += partial[((size_t)b * 16 + c) * MSn + m];
    ctx[(size_t)b * MSn + m] = s;
}

extern "C" void kernel_launch(void* const* d_in, const int* in_sizes, int n_in,
                              void* d_out, int out_size, void* d_ws, size_t ws_size,
                              hipStream_t stream) {
    const float* query = (const float*)d_in[0];
    const float* keys  = (const float*)d_in[1];
    const float* Wq    = (const float*)d_in[2];
    const float* Wm    = (const float*)d_in[3];
    const float* Wa    = (const float*)d_in[4];

    float* ctx_out   = (float*)d_out;                    // [64][512]
    float* score_out = (float*)d_out + (size_t)Bn * MSn; // [64][2048]

    char* ws = (char*)d_ws;
    float* ws_pq      = (float*)(ws);                    // 128 KB
    float* ws_weight  = (float*)(ws + 131072);           // 512 KB
    float* ws_spart   = (float*)(ws + 655360);           // 1 MB  [2][64][2048]
    float* ws_partial = (float*)(ws + 1703936);          // 2 MB  [64][16][512]
    unsigned short* ws_wmbf = (unsigned short*)(ws + 3801088);  // 512 KB

    cvt_kernel<<<(Un * MSn / 4) / 256, 256, 0, stream>>>(Wm, ws_wmbf);
    pq_kernel<<<dim3(Bn, 4), 128, 0, stream>>>(query, Wq, ws_pq);
    score_kernel<<<dim3((Tn / TM) * 2, Bn), 256, 0, stream>>>(keys, ws_wmbf, ws_pq, Wa, ws_spart);
    softmax_kernel<<<Bn, 256, 0, stream>>>(ws_spart, score_out, ws_weight);
    ctx_partial_kernel<<<dim3(Bn, 16), 128, 0, stream>>>(keys, ws_weight, ws_partial);
    ctx_reduce_kernel<<<Bn, 512, 0, stream>>>(ws_partial, ctx_out);
}

// Round 4
// 225.479 us; speedup vs baseline: 1.4415x; 1.0228x over previous
//
#include <hip/hip_runtime.h>
#include <cstdint>
#include <cstddef>

#define Bn 64
#define Tn 2048
#define Un 512
#define QSn 512
#define MSn 512

using f32x16 = __attribute__((ext_vector_type(16))) float;
using bf16x8 = __attribute__((ext_vector_type(8))) short;

__device__ __forceinline__ unsigned short f2bf(float x) {
    unsigned int u = __float_as_uint(x);
    u += 0x7FFFu + ((u >> 16) & 1u);
    return (unsigned short)(u >> 16);
}

__device__ __forceinline__ unsigned int pk2bf(float lo, float hi) {
    unsigned int r;
    asm("v_cvt_pk_bf16_f32 %0, %1, %2" : "=v"(r) : "v"(lo), "v"(hi));
    return r;
}

__device__ __forceinline__ float tanh_fast(float x) {
    // tanh(x) = 1 - 2/(e^{2x}+1). No clamp needed: exp->inf gives 1, exp->0 gives -1.
    float e = exp2f(x * 2.885390043258667f);   // e^{2x}
    return 1.f - 2.f * __builtin_amdgcn_rcpf(e + 1.f);
}

// ---------------- Wm f32 -> bf16 pre-convert ----------------
__global__ __launch_bounds__(256) void cvt_kernel(const float* __restrict__ src,
                                                  unsigned short* __restrict__ dst) {
    int i = blockIdx.x * 256 + threadIdx.x;  // one float4 per thread
    float4 v = *(const float4*)(src + (size_t)i * 4);
    ushort4 h = { f2bf(v.x), f2bf(v.y), f2bf(v.z), f2bf(v.w) };
    *(ushort4*)&dst[(size_t)i * 4] = h;
}

// ---------------- pq = query @ Wq^T : [B,U] ----------------
__global__ __launch_bounds__(128) void pq_kernel(const float* __restrict__ query,
                                                 const float* __restrict__ Wq,
                                                 float* __restrict__ pq) {
    __shared__ float ql[QSn];
    const int b = blockIdx.x;
    const int quad = blockIdx.y;
    const int tid = threadIdx.x;
    for (int i = tid; i < QSn; i += 128) ql[i] = query[(size_t)b * QSn + i];
    __syncthreads();
    const int u = quad * 128 + tid;
    const float* w = Wq + (size_t)u * QSn;
    float a0 = 0.f, a1 = 0.f;
    #pragma unroll 4
    for (int k = 0; k < QSn; k += 8) {
        float4 w0 = *(const float4*)(w + k);
        float4 w1 = *(const float4*)(w + k + 4);
        float4 q0 = *(const float4*)(ql + k);
        float4 q1 = *(const float4*)(ql + k + 4);
        a0 += w0.x * q0.x + w0.y * q0.y + w0.z * q0.z + w0.w * q0.w;
        a1 += w1.x * q1.x + w1.y * q1.y + w1.z * q1.z + w1.w * q1.w;
    }
    pq[(size_t)b * Un + u] = a0 + a1;
}

// ---------------- fused score GEMM (v4: counted-vmcnt pipeline) ----------------
// 256 threads = 4 waves. Block tile 64t x 256u (U split over 2 blocks, merged in
// softmax). Wave tile 64x64 = 2x2 mfma_32x32x16.
// Pipeline per kt: issue A[kt+1] (HBM) then B[kt+1] (L2, into reg dbuf);
// MFMA on A[kt] (LDS) x B[kt] (regs issued LAST iter -> counted vmcnt, ~0 wait);
// cvt+ds_write A[kt+1]; lgkmcnt(0)+raw s_barrier (NO vmcnt drain -> B loads
// stay in flight across the barrier).
#define TM 64
#define BKt 64

__global__ __launch_bounds__(256, 3) void score_kernel(const float* __restrict__ keys,
                                                       const unsigned short* __restrict__ WmB,
                                                       const float* __restrict__ pq,
                                                       const float* __restrict__ Wa,
                                                       float* __restrict__ spart) {
    __shared__ __align__(16) unsigned short Alds[2][TM * BKt];  // 16 KB
    __shared__ float sc_lds[4][TM];

    const int tid = threadIdx.x;
    const int lane = tid & 63;
    const int w = tid >> 6;
    const int lc = lane & 31;
    const int l5 = lane >> 5;
    const int b = blockIdx.y;
    const int tt = blockIdx.x >> 1;
    const int uh = blockIdx.x & 1;
    const int t0 = tt * TM;
    const int u0 = uh * 256 + w * 64;

    // A staging: thread owns row srow, two 8-elem granules scg, scg+1
    const int srow = tid >> 2;
    const int scg  = (tid & 3) * 2;
    const float* gA = keys + ((size_t)(b * Tn + t0 + srow)) * MSn + scg * 8;
    const int woff0 = srow * BKt + ((scg ^ (srow & 7)) * 8);
    const int woff1 = srow * BKt + (((scg + 1) ^ (srow & 7)) * 8);

    const unsigned short* gB0 = WmB + ((size_t)(u0 + lc)) * MSn + l5 * 8;
    const unsigned short* gB1 = gB0 + (size_t)32 * MSn;

    f32x16 acc[2][2];
    #pragma unroll
    for (int mf = 0; mf < 2; ++mf)
        #pragma unroll
        for (int nf = 0; nf < 2; ++nf)
            #pragma unroll
            for (int r = 0; r < 16; ++r) acc[mf][nf][r] = 0.f;

    bf16x8 breg[2][4][2];

    // ---- prologue: A[0] loads, B[0] loads, write A[0], barrier
    {
        float4 a0 = *(const float4*)(gA);
        float4 a1 = *(const float4*)(gA + 4);
        float4 a2 = *(const float4*)(gA + 8);
        float4 a3 = *(const float4*)(gA + 12);
        __builtin_amdgcn_sched_barrier(0);
        #pragma unroll
        for (int ks = 0; ks < 4; ++ks) {
            breg[0][ks][0] = *(const bf16x8*)(gB0 + ks * 16);
            breg[0][ks][1] = *(const bf16x8*)(gB1 + ks * 16);
        }
        __builtin_amdgcn_sched_barrier(0);
        uint4 h0 = { pk2bf(a0.x, a0.y), pk2bf(a0.z, a0.w), pk2bf(a1.x, a1.y), pk2bf(a1.z, a1.w) };
        uint4 h1 = { pk2bf(a2.x, a2.y), pk2bf(a2.z, a2.w), pk2bf(a3.x, a3.y), pk2bf(a3.z, a3.w) };
        *(uint4*)&Alds[0][woff0] = h0;
        *(uint4*)&Alds[0][woff1] = h1;
    }
    asm volatile("s_waitcnt lgkmcnt(0)" ::: "memory");
    __builtin_amdgcn_s_barrier();

    #pragma unroll
    for (int kt = 0; kt < 8; ++kt) {
        const int cur = kt & 1;
        const int nxt = cur ^ 1;

        float4 a0, a1, a2, a3;
        if (kt < 7) {
            // A loads for kt+1 FIRST (HBM; waited at the ds_write below, vmcnt(8))
            const float* g = gA + (kt + 1) * BKt;
            a0 = *(const float4*)(g);
            a1 = *(const float4*)(g + 4);
            a2 = *(const float4*)(g + 8);
            a3 = *(const float4*)(g + 12);
            __builtin_amdgcn_sched_barrier(0);
            // B loads for kt+1 (L2; consumed NEXT iter -> counted vmcnt, hidden)
            #pragma unroll
            for (int ks = 0; ks < 4; ++ks) {
                breg[nxt][ks][0] = *(const bf16x8*)(gB0 + (kt + 1) * BKt + ks * 16);
                breg[nxt][ks][1] = *(const bf16x8*)(gB1 + (kt + 1) * BKt + ks * 16);
            }
            __builtin_amdgcn_sched_barrier(0);
        }

        // MFMA phase: A[kt] from LDS, B[kt] from regs (issued last iter)
        #pragma unroll
        for (int ks = 0; ks < 4; ++ks) {
            bf16x8 af[2];
            #pragma unroll
            for (int mf = 0; mf < 2; ++mf) {
                int r = mf * 32 + lc;
                int g = ks * 2 + l5;
                af[mf] = *(const bf16x8*)&Alds[cur][r * BKt + ((g ^ (r & 7)) * 8)];
            }
            #pragma unroll
            for (int mf = 0; mf < 2; ++mf)
                #pragma unroll
                for (int nf = 0; nf < 2; ++nf)
                    acc[mf][nf] = __builtin_amdgcn_mfma_f32_32x32x16_bf16(
                        af[mf], breg[cur][ks][nf], acc[mf][nf], 0, 0, 0);
        }

        // stage A[kt+1] into the other buffer
        if (kt < 7) {
            uint4 h0 = { pk2bf(a0.x, a0.y), pk2bf(a0.z, a0.w), pk2bf(a1.x, a1.y), pk2bf(a1.z, a1.w) };
            uint4 h1 = { pk2bf(a2.x, a2.y), pk2bf(a2.z, a2.w), pk2bf(a3.x, a3.y), pk2bf(a3.z, a3.w) };
            *(uint4*)&Alds[nxt][woff0] = h0;
            *(uint4*)&Alds[nxt][woff1] = h1;
        }
        // drain LDS ops only; B global loads stay in flight across the barrier
        asm volatile("s_waitcnt lgkmcnt(0)" ::: "memory");
        __builtin_amdgcn_s_barrier();
    }

    // ---- epilogue: partial score = sum_u tanh(vals + pq[u]) * Wa[u]
    float pqv[2], wav[2];
    #pragma unroll
    for (int nf = 0; nf < 2; ++nf) {
        int u = u0 + nf * 32 + lc;
        pqv[nf] = pq[(size_t)b * Un + u];
        wav[nf] = Wa[u];
    }
    #pragma unroll
    for (int mf = 0; mf < 2; ++mf) {
        #pragma unroll
        for (int r = 0; r < 16; ++r) {
            float s = tanh_fast(acc[mf][0][r] + pqv[0]) * wav[0]
                    + tanh_fast(acc[mf][1][r] + pqv[1]) * wav[1];
            s += __shfl_xor(s, 16);
            s += __shfl_xor(s, 8);
            s += __shfl_xor(s, 4);
            s += __shfl_xor(s, 2);
            s += __shfl_xor(s, 1);
            if (lc == 0)
                sc_lds[w][mf * 32 + (r & 3) + 8 * (r >> 2) + 4 * l5] = s;
        }
    }
    __syncthreads();
    if (tid < TM) {
        float s = sc_lds[0][tid] + sc_lds[1][tid] + sc_lds[2][tid] + sc_lds[3][tid];
        spart[((size_t)(uh * Bn + b)) * Tn + t0 + tid] = s;
    }
}

// ---------------- merge partials + softmax ----------------
__global__ __launch_bounds__(256) void softmax_kernel(const float* __restrict__ spart,
                                                      float* __restrict__ score_out,
                                                      float* __restrict__ weight) {
    const int b = blockIdx.x, tid = threadIdx.x;
    const int lane = tid & 63, wid = tid >> 6;
    __shared__ float red[4];
    const float* s0 = spart + (size_t)b * Tn;
    const float* s1 = spart + ((size_t)(Bn + b)) * Tn;
    float v[8];
    float mx = -1e30f;
    #pragma unroll
    for (int i = 0; i < 8; ++i) {
        int t = tid + i * 256;
        v[i] = s0[t] + s1[t];
        score_out[(size_t)b * Tn + t] = v[i];
        mx = fmaxf(mx, v[i]);
    }
    #pragma unroll
    for (int off = 32; off; off >>= 1) mx = fmaxf(mx, __shfl_xor(mx, off));
    if (lane == 0) red[wid] = mx;
    __syncthreads();
    mx = fmaxf(fmaxf(red[0], red[1]), fmaxf(red[2], red[3]));
    float sum = 0.f;
    #pragma unroll
    for (int i = 0; i < 8; ++i) { v[i] = expf(v[i] - mx); sum += v[i]; }
    #pragma unroll
    for (int off = 32; off; off >>= 1) sum += __shfl_xor(sum, off);
    __syncthreads();
    if (lane == 0) red[wid] = sum;
    __syncthreads();
    sum = red[0] + red[1] + red[2] + red[3];
    float inv = 1.f / sum;
    #pragma unroll
    for (int i = 0; i < 8; ++i) weight[(size_t)b * Tn + tid + i * 256] = v[i] * inv;
}

// ---------------- context partials: 16 t-chunks per batch, float4/lane ----------------
__global__ __launch_bounds__(128) void ctx_partial_kernel(const float* __restrict__ keys,
                                                          const float* __restrict__ weight,
                                                          float* __restrict__ partial) {
    __shared__ float wl[128];
    const int b = blockIdx.x, chunk = blockIdx.y, tid = threadIdx.x;
    const int t0 = chunk * 128;
    if (tid < 128) wl[tid] = weight[(size_t)b * Tn + t0 + tid];
    __syncthreads();
    float4 acc = { 0.f, 0.f, 0.f, 0.f };
    const float4* kp = (const float4*)(keys + ((size_t)b * Tn + t0) * MSn) + tid;
    #pragma unroll 4
    for (int t = 0; t < 128; ++t) {
        float4 kv = kp[(size_t)t * (MSn / 4)];
        float w = wl[t];
        acc.x += w * kv.x;
        acc.y += w * kv.y;
        acc.z += w * kv.z;
        acc.w += w * kv.w;
    }
    *(float4*)&partial[((size_t)b * 16 + chunk) * MSn + tid * 4] = acc;
}

// ---------------- reduce partials -> total_context ----------------
__global__ __launch_bounds__(512) void ctx_reduce_kernel(const float* __restrict__ partial,
                                                         float* __restrict__ ctx) {
    const int b = blockIdx.x, m = threadIdx.x;
    float s = 0.f;
    #pragma unroll
    for (int c = 0; c < 16; ++c) s += partial[((size_t)b * 16 + c) * MSn + m];
    ctx[(size_t)b * MSn + m] = s;
}

extern "C" void kernel_launch(void* const* d_in, const int* in_sizes, int n_in,
                              void* d_out, int out_size, void* d_ws, size_t ws_size,
                              hipStream_t stream) {
    const float* query = (const float*)d_in[0];
    const float* keys  = (const float*)d_in[1];
    const float* Wq    = (const float*)d_in[2];
    const float* Wm    = (const float*)d_in[3];
    const float* Wa    = (const float*)d_in[4];

    float* ctx_out   = (float*)d_out;                    // [64][512]
    float* score_out = (float*)d_out + (size_t)Bn * MSn; // [64][2048]

    char* ws = (char*)d_ws;
    float* ws_pq      = (float*)(ws);                    // 128 KB
    float* ws_weight  = (float*)(ws + 131072);           // 512 KB
    float* ws_spart   = (float*)(ws + 655360);           // 1 MB  [2][64][2048]
    float* ws_partial = (float*)(ws + 1703936);          // 2 MB  [64][16][512]
    unsigned short* ws_wmbf = (unsigned short*)(ws + 3801088);  // 512 KB

    cvt_kernel<<<(Un * MSn / 4) / 256, 256, 0, stream>>>(Wm, ws_wmbf);
    pq_kernel<<<dim3(Bn, 4), 128, 0, stream>>>(query, Wq, ws_pq);
    score_kernel<<<dim3((Tn / TM) * 2, Bn), 256, 0, stream>>>(keys, ws_wmbf, ws_pq, Wa, ws_spart);
    softmax_kernel<<<Bn, 256, 0, stream>>>(ws_spart, score_out, ws_weight);
    ctx_partial_kernel<<<dim3(Bn, 16), 128, 0, stream>>>(keys, ws_weight, ws_partial);
    ctx_reduce_kernel<<<Bn, 512, 0, stream>>>(ws_partial, ctx_out);
}